// Round 1
// baseline (2245.202 us; speedup 1.0000x reference)
//
#include <hip/hip_runtime.h>
#include <cstdint>
#include <cstddef>

typedef unsigned short u16;
typedef __bf16 bf16x8 __attribute__((ext_vector_type(8)));
typedef float floatx4 __attribute__((ext_vector_type(4)));
typedef u16 u16x8 __attribute__((ext_vector_type(8)));

#define NHEAD 16
#define DHEAD 64
#define BATCH 4
#define SEQ 2048
#define DMODEL 1024

// round-to-nearest-even fp32 -> bf16
__device__ __forceinline__ u16 f2b(float f) {
  union { float f; unsigned u; } x; x.f = f;
  unsigned r = x.u + 0x7fffu + ((x.u >> 16) & 1u);
  return (u16)(r >> 16);
}

__device__ __forceinline__ floatx4 mfma16(bf16x8 a, bf16x8 b, floatx4 c) {
  return __builtin_amdgcn_mfma_f32_16x16x32_bf16(a, b, c, 0, 0, 0);
}

// ---------------------------------------------------------------------------
// Weight transpose+convert: w[d][c] fp32 (1024x1024) -> wt[c][d] bf16
// ---------------------------------------------------------------------------
__global__ __launch_bounds__(256) void wtrans(const float* __restrict__ w,
                                              u16* __restrict__ wt) {
  __shared__ u16 tile[64 * 68];
  const int t = threadIdx.x;
  const int d0 = blockIdx.x * 64, c0 = blockIdx.y * 64;
#pragma unroll
  for (int s = 0; s < 4; ++s) {
    int dd = (t >> 4) + s * 16;
    int cc = (t & 15) * 4;
    float4 v = *(const float4*)(w + (size_t)(d0 + dd) * DMODEL + c0 + cc);
    u16* p = &tile[dd * 68 + cc];
    p[0] = f2b(v.x); p[1] = f2b(v.y); p[2] = f2b(v.z); p[3] = f2b(v.w);
  }
  __syncthreads();
#pragma unroll
  for (int s = 0; s < 2; ++s) {
    int cc = (t >> 3) + s * 32;
    int dd = (t & 7) * 8;
    u16x8 rv;
#pragma unroll
    for (int j = 0; j < 8; ++j) rv[j] = tile[(dd + j) * 68 + cc];
    *(u16x8*)(wt + (size_t)(c0 + cc) * DMODEL + d0 + dd) = rv;
  }
}

// ---------------------------------------------------------------------------
// 128x128-tile bf16 MFMA GEMM, K=1024 in 64-chunks. 256 thr = 4 waves,
// each wave 64x64 (4x4 MFMA 16x16x32 tiles).
// mode 0: C=A(fp32)@W + bias -> bf16 in (B,H,L,DK) layout    (q/k proj)
// mode 1: same but store transposed (B,H,DK,L) layout         (v proj)
// mode 2: C=Ab(bf16)@W + bias + resid -> fp32 row-major       (fc + residual)
// ---------------------------------------------------------------------------
__global__ __launch_bounds__(256) void gemm128(
    const float* __restrict__ Af, const u16* __restrict__ Ab,
    const u16* __restrict__ WT, const float* __restrict__ bias,
    u16* __restrict__ outb, float* __restrict__ outf,
    const float* __restrict__ resid, int mode) {
  __shared__ __align__(16) u16 sm[2 * 128 * 72];
  u16* sA = sm;
  u16* sB = sm + 128 * 72;
  const int t = threadIdx.x;
  const int w = t >> 6, lane = t & 63, quad = lane >> 4, ln = lane & 15;
  const int Mb = blockIdx.x * 128, Nb = blockIdx.y * 128;
  const int wr = (w >> 1) * 64, wc = (w & 1) * 64;
  floatx4 acc[4][4] = {};
#pragma unroll 1
  for (int kc = 0; kc < 16; ++kc) {
    const int k0 = kc * 64;
    __syncthreads();
    if (mode == 2) {
#pragma unroll
      for (int s = 0; s < 4; ++s) {
        int r = (t >> 3) + s * 32, off = (t & 7) * 8;
        *(u16x8*)(&sA[r * 72 + off]) =
            *(const u16x8*)(Ab + (size_t)(Mb + r) * DMODEL + k0 + off);
      }
    } else {
#pragma unroll
      for (int s = 0; s < 8; ++s) {
        int r = (t >> 4) + s * 16, c = (t & 15) * 4;
        float4 v = *(const float4*)(Af + (size_t)(Mb + r) * DMODEL + k0 + c);
        u16* p = &sA[r * 72 + c];
        p[0] = f2b(v.x); p[1] = f2b(v.y); p[2] = f2b(v.z); p[3] = f2b(v.w);
      }
    }
#pragma unroll
    for (int s = 0; s < 4; ++s) {
      int r = (t >> 3) + s * 32, off = (t & 7) * 8;
      *(u16x8*)(&sB[r * 72 + off]) =
          *(const u16x8*)(WT + (size_t)(Nb + r) * DMODEL + k0 + off);
    }
    __syncthreads();
#pragma unroll
    for (int ks = 0; ks < 2; ++ks) {
      bf16x8 af[4], bfr[4];
#pragma unroll
      for (int m = 0; m < 4; ++m)
        af[m] = *(const bf16x8*)(&sA[(wr + m * 16 + ln) * 72 + quad * 8 + ks * 32]);
#pragma unroll
      for (int n = 0; n < 4; ++n)
        bfr[n] = *(const bf16x8*)(&sB[(wc + n * 16 + ln) * 72 + quad * 8 + ks * 32]);
#pragma unroll
      for (int m = 0; m < 4; ++m)
#pragma unroll
        for (int n = 0; n < 4; ++n)
          acc[m][n] = mfma16(af[m], bfr[n], acc[m][n]);
    }
  }
  float bv[4];
#pragma unroll
  for (int n = 0; n < 4; ++n) bv[n] = bias[Nb + wc + n * 16 + ln];

  if (mode == 0) {
#pragma unroll
    for (int m = 0; m < 4; ++m)
#pragma unroll
      for (int n = 0; n < 4; ++n)
#pragma unroll
        for (int rr = 0; rr < 4; ++rr) {
          int row = Mb + wr + m * 16 + quad * 4 + rr;
          int c = Nb + wc + n * 16 + ln;
          int bi = row >> 11, lq = row & 2047, h = c >> 6, dk = c & 63;
          outb[(((size_t)bi * NHEAD + h) * SEQ + lq) * DHEAD + dk] =
              f2b(acc[m][n][rr] + bv[n]);
        }
  } else if (mode == 2) {
#pragma unroll
    for (int m = 0; m < 4; ++m)
#pragma unroll
      for (int n = 0; n < 4; ++n)
#pragma unroll
        for (int rr = 0; rr < 4; ++rr) {
          int row = Mb + wr + m * 16 + quad * 4 + rr;
          int c = Nb + wc + n * 16 + ln;
          size_t idx = (size_t)row * DMODEL + c;
          outf[idx] = acc[m][n][rr] + bv[n] + resid[idx];
        }
  } else {  // mode 1: transpose to (B,H,DK,L) through LDS
    __syncthreads();
    u16* tb = sm;  // stride 132, 128x132 fits in 2*128*72
#pragma unroll
    for (int m = 0; m < 4; ++m)
#pragma unroll
      for (int n = 0; n < 4; ++n)
#pragma unroll
        for (int rr = 0; rr < 4; ++rr) {
          int rl = wr + m * 16 + quad * 4 + rr;
          int cl = wc + n * 16 + ln;
          tb[rl * 132 + cl] = f2b(acc[m][n][rr] + bv[n]);
        }
    __syncthreads();
    for (int s = 0; s < 64; ++s) {
      int flat = s * 256 + t;
      int cl = flat >> 7, lkl = flat & 127;
      int c = Nb + cl, h = c >> 6, dk = c & 63;
      int lk = Mb + lkl, bi = lk >> 11, lkq = lk & 2047;
      outb[(((size_t)bi * NHEAD + h) * DHEAD + dk) * SEQ + lkq] =
          tb[lkl * 132 + cl];
    }
  }
}

// ---------------------------------------------------------------------------
// Two-pass flash attention per (b,h,64-row Q tile). Pass A: online (m,l)
// stats over all K. Pass B: recompute scores, write normalized P (fp32) to
// d_out attn region, accumulate O = P@V via MFMA. Mask dtype auto-detected.
// ---------------------------------------------------------------------------
__global__ __launch_bounds__(256) void attn_k(
    const u16* __restrict__ qh, const u16* __restrict__ kh,
    const u16* __restrict__ vT, const void* __restrict__ maskp,
    float* __restrict__ attn_o, u16* __restrict__ ao) {
  __shared__ __align__(16) u16 qs[64 * 72];
  __shared__ __align__(16) u16 ks_[64 * 72];
  __shared__ __align__(16) u16 vs[64 * 72];
  __shared__ __align__(16) u16 ps[64 * 72];
  __shared__ float ms[64], ls[64];
  const int t = threadIdx.x;
  const int w = t >> 6, lane = t & 63, quad = lane >> 4, ln = lane & 15;
  const int qt = blockIdx.x, bh = blockIdx.y;
  const int b = bh >> 4;
  const int q0 = qt * 64;
  const float SC = 0.18033688011112042f;  // log2(e)/8

  // mask dtype detection: any of first 64 words > 1 => byte mask
  unsigned mw = ((const unsigned*)maskp)[lane];
  const bool bytemask = __ballot(mw > 1u) != 0ull;
  const unsigned char* m8 = (const unsigned char*)maskp;
  const unsigned* m32 = (const unsigned*)maskp;
  const size_t mbase = (size_t)b * SEQ * SEQ;

  // stage Q tile (64x64)
#pragma unroll
  for (int s = 0; s < 2; ++s) {
    int r = (t >> 3) + s * 32, off = (t & 7) * 8;
    *(u16x8*)(&qs[r * 72 + off]) =
        *(const u16x8*)(qh + ((size_t)bh * SEQ + q0 + r) * DHEAD + off);
  }
  float mrun[4], lrun[4];
#pragma unroll
  for (int rr = 0; rr < 4; ++rr) { mrun[rr] = -1e30f; lrun[rr] = 0.f; }

  // ---- pass A: stats
#pragma unroll 1
  for (int kt = 0; kt < 32; ++kt) {
    __syncthreads();
#pragma unroll
    for (int s = 0; s < 2; ++s) {
      int r = (t >> 3) + s * 32, off = (t & 7) * 8;
      *(u16x8*)(&ks_[r * 72 + off]) =
          *(const u16x8*)(kh + ((size_t)bh * SEQ + kt * 64 + r) * DHEAD + off);
    }
    __syncthreads();
    floatx4 sc[4] = {};
#pragma unroll
    for (int kss = 0; kss < 2; ++kss) {
      bf16x8 a = *(const bf16x8*)(&qs[(w * 16 + ln) * 72 + quad * 8 + kss * 32]);
#pragma unroll
      for (int n = 0; n < 4; ++n) {
        bf16x8 bb = *(const bf16x8*)(&ks_[(n * 16 + ln) * 72 + quad * 8 + kss * 32]);
        sc[n] = mfma16(a, bb, sc[n]);
      }
    }
#pragma unroll
    for (int rr = 0; rr < 4; ++rr) {
      int qrow = q0 + w * 16 + quad * 4 + rr;
      float tv[4];
#pragma unroll
      for (int n = 0; n < 4; ++n) {
        int kcol = kt * 64 + n * 16 + ln;
        size_t mi = mbase + (size_t)qrow * SEQ + kcol;
        bool blk = bytemask ? (m8[mi] != 0) : (m32[mi] != 0);
        tv[n] = blk ? -1e30f : sc[n][rr] * SC;
      }
      float cm = fmaxf(fmaxf(tv[0], tv[1]), fmaxf(tv[2], tv[3]));
#pragma unroll
      for (int o = 1; o < 16; o <<= 1) cm = fmaxf(cm, __shfl_xor(cm, o));
      float cs = exp2f(tv[0] - cm) + exp2f(tv[1] - cm) +
                 exp2f(tv[2] - cm) + exp2f(tv[3] - cm);
#pragma unroll
      for (int o = 1; o < 16; o <<= 1) cs += __shfl_xor(cs, o);
      float mnew = fmaxf(mrun[rr], cm);
      lrun[rr] = lrun[rr] * exp2f(mrun[rr] - mnew) + cs * exp2f(cm - mnew);
      mrun[rr] = mnew;
    }
  }
  if (ln == 0) {
#pragma unroll
    for (int rr = 0; rr < 4; ++rr) {
      ms[w * 16 + quad * 4 + rr] = mrun[rr];
      ls[w * 16 + quad * 4 + rr] = lrun[rr];
    }
  }
  __syncthreads();
  float mf[4], il[4];
#pragma unroll
  for (int rr = 0; rr < 4; ++rr) {
    mf[rr] = ms[w * 16 + quad * 4 + rr];
    il[rr] = 1.0f / ls[w * 16 + quad * 4 + rr];
  }

  // ---- pass B: recompute, write P, accumulate O
  floatx4 oa[4] = {};
#pragma unroll 1
  for (int kt = 0; kt < 32; ++kt) {
    __syncthreads();
#pragma unroll
    for (int s = 0; s < 2; ++s) {
      int r = (t >> 3) + s * 32, off = (t & 7) * 8;
      *(u16x8*)(&ks_[r * 72 + off]) =
          *(const u16x8*)(kh + ((size_t)bh * SEQ + kt * 64 + r) * DHEAD + off);
      *(u16x8*)(&vs[r * 72 + off]) =
          *(const u16x8*)(vT + ((size_t)bh * DHEAD + r) * SEQ + kt * 64 + off);
    }
    __syncthreads();
    floatx4 sc[4] = {};
#pragma unroll
    for (int kss = 0; kss < 2; ++kss) {
      bf16x8 a = *(const bf16x8*)(&qs[(w * 16 + ln) * 72 + quad * 8 + kss * 32]);
#pragma unroll
      for (int n = 0; n < 4; ++n) {
        bf16x8 bb = *(const bf16x8*)(&ks_[(n * 16 + ln) * 72 + quad * 8 + kss * 32]);
        sc[n] = mfma16(a, bb, sc[n]);
      }
    }
#pragma unroll
    for (int rr = 0; rr < 4; ++rr) {
      int qrow = q0 + w * 16 + quad * 4 + rr;
#pragma unroll
      for (int n = 0; n < 4; ++n) {
        int kcol = kt * 64 + n * 16 + ln;
        size_t mi = mbase + (size_t)qrow * SEQ + kcol;
        bool blk = bytemask ? (m8[mi] != 0) : (m32[mi] != 0);
        float tvv = blk ? -1e30f : sc[n][rr] * SC;
        float pn = exp2f(tvv - mf[rr]) * il[rr];
        attn_o[(size_t)bh * SEQ * SEQ + (size_t)qrow * SEQ + kcol] = pn;
        ps[(w * 16 + quad * 4 + rr) * 72 + n * 16 + ln] = f2b(pn);
      }
    }
    __syncthreads();
#pragma unroll
    for (int kss = 0; kss < 2; ++kss) {
      bf16x8 a = *(const bf16x8*)(&ps[(w * 16 + ln) * 72 + quad * 8 + kss * 32]);
#pragma unroll
      for (int n = 0; n < 4; ++n) {
        bf16x8 bb = *(const bf16x8*)(&vs[(n * 16 + ln) * 72 + quad * 8 + kss * 32]);
        oa[n] = mfma16(a, bb, oa[n]);
      }
    }
  }
  // store O (normalized already) to attn-out staging (b, lq, h*64+dv) bf16
#pragma unroll
  for (int n = 0; n < 4; ++n)
#pragma unroll
    for (int rr = 0; rr < 4; ++rr) {
      int row = q0 + w * 16 + quad * 4 + rr;
      ao[((size_t)b * SEQ + row) * DMODEL + (bh & 15) * DHEAD + n * 16 + ln] =
          f2b(oa[n][rr]);
    }
}

// ---------------------------------------------------------------------------
extern "C" void kernel_launch(void* const* d_in, const int* in_sizes, int n_in,
                              void* d_out, int out_size, void* d_ws,
                              size_t ws_size, hipStream_t stream) {
  (void)in_sizes; (void)n_in; (void)out_size; (void)ws_size;
  const float* q = (const float*)d_in[0];
  const float* k = (const float*)d_in[1];
  const float* v = (const float*)d_in[2];
  const void* mask = d_in[3];
  const float* w_qs = (const float*)d_in[4];
  const float* b_qs = (const float*)d_in[5];
  const float* w_ks = (const float*)d_in[6];
  const float* b_ks = (const float*)d_in[7];
  const float* w_vs = (const float*)d_in[8];
  const float* b_vs = (const float*)d_in[9];
  const float* fc_w = (const float*)d_in[10];
  const float* fc_b = (const float*)d_in[11];

  char* ws = (char*)d_ws;
  const size_t WSZ = (size_t)DMODEL * DMODEL * 2;         // 2 MB per weight
  const size_t HSZ = (size_t)BATCH * NHEAD * SEQ * DHEAD * 2;  // 16 MB
  u16* wqT = (u16*)(ws + 0 * WSZ);
  u16* wkT = (u16*)(ws + 1 * WSZ);
  u16* wvT = (u16*)(ws + 2 * WSZ);
  u16* fcT = (u16*)(ws + 3 * WSZ);
  u16* qh = (u16*)(ws + 4 * WSZ);
  u16* kh = (u16*)(ws + 4 * WSZ + HSZ);
  u16* vhT = (u16*)(ws + 4 * WSZ + 2 * HSZ);
  u16* ao = (u16*)(ws + 4 * WSZ + 3 * HSZ);

  float* out0 = (float*)d_out;
  float* attn = out0 + (size_t)BATCH * SEQ * DMODEL;

  dim3 tgrid(16, 16);
  wtrans<<<tgrid, 256, 0, stream>>>(w_qs, wqT);
  wtrans<<<tgrid, 256, 0, stream>>>(w_ks, wkT);
  wtrans<<<tgrid, 256, 0, stream>>>(w_vs, wvT);
  wtrans<<<tgrid, 256, 0, stream>>>(fc_w, fcT);

  dim3 ggrid(64, 8);
  gemm128<<<ggrid, 256, 0, stream>>>(q, nullptr, wqT, b_qs, qh, nullptr, nullptr, 0);
  gemm128<<<ggrid, 256, 0, stream>>>(k, nullptr, wkT, b_ks, kh, nullptr, nullptr, 0);
  gemm128<<<ggrid, 256, 0, stream>>>(v, nullptr, wvT, b_vs, vhT, nullptr, nullptr, 1);

  attn_k<<<dim3(32, 64), 256, 0, stream>>>(qh, kh, vhT, mask, attn, ao);

  gemm128<<<ggrid, 256, 0, stream>>>(nullptr, ao, fcT, fc_b, nullptr, out0, q, 2);
}